// Round 2
// baseline (1365.113 us; speedup 1.0000x reference)
//
#include <hip/hip_runtime.h>
#include <stdint.h>

// Problem constants
#define NTOK 1024          // N*T
#define DIM  512           // D
#define NH   8             // H
#define DKH  128           // DK
#define HALFD 64           // DK/2
#define EXP  256           // E
#define EE   65536         // E*E
#define HDK  1024          // H*DK

typedef short bf16x8 __attribute__((ext_vector_type(8)));
typedef float f32x4  __attribute__((ext_vector_type(4)));

__device__ __forceinline__ unsigned short f2bf(float f) {
    unsigned u = __float_as_uint(f);
    u += 0x7fff + ((u >> 16) & 1);     // round-to-nearest-even
    return (unsigned short)(u >> 16);
}
__device__ __forceinline__ float bf2f(unsigned short h) {
    return __uint_as_float((unsigned)h << 16);
}

// ---------------- fp32 -> bf16 convert (8 elems/thread) ----------------
__global__ void cvt_bf16(const float* __restrict__ src,
                         unsigned short* __restrict__ dst, int n8) {
    int i = blockIdx.x * blockDim.x + threadIdx.x;
    if (i >= n8) return;
    const float4* s4 = (const float4*)src;
    float4 a = s4[2 * i], b = s4[2 * i + 1];
    union { unsigned short u[8]; uint4 v; } r;
    r.u[0] = f2bf(a.x); r.u[1] = f2bf(a.y); r.u[2] = f2bf(a.z); r.u[3] = f2bf(a.w);
    r.u[4] = f2bf(b.x); r.u[5] = f2bf(b.y); r.u[6] = f2bf(b.z); r.u[7] = f2bf(b.w);
    ((uint4*)dst)[i] = r.v;
}

// ------------- fp32 -> bf16 hi/lo split (4 elems/thread) --------------
// x ~= hi + lo, each bf16; residual ~2^-18 relative.
__global__ void cvt_bf16_hilo(const float* __restrict__ src,
                              unsigned short* __restrict__ hi,
                              unsigned short* __restrict__ lo, int n4) {
    int i = blockIdx.x * blockDim.x + threadIdx.x;
    if (i >= n4) return;
    float4 a = ((const float4*)src)[i];
    union { unsigned short u[4]; uint2 v; } rh, rl;
    float x[4] = {a.x, a.y, a.z, a.w};
#pragma unroll
    for (int j = 0; j < 4; j++) {
        unsigned short h = f2bf(x[j]);
        rh.u[j] = h;
        rl.u[j] = f2bf(x[j] - bf2f(h));
    }
    ((uint2*)hi)[i] = rh.v;
    ((uint2*)lo)[i] = rl.v;
}

// ---------------- w_up (EE x D) fp32 -> WuT (D x EE) bf16 ----------------
__global__ void transpose_wu(const float* __restrict__ wu,
                             unsigned short* __restrict__ wuT) {
    __shared__ float tile[32][33];
    int d0 = blockIdx.x * 32;
    int e0 = blockIdx.y * 32;
    int tx = threadIdx.x, ty = threadIdx.y;
#pragma unroll
    for (int i = 0; i < 4; i++)
        tile[ty + 8 * i][tx] = wu[(size_t)(e0 + ty + 8 * i) * DIM + d0 + tx];
    __syncthreads();
#pragma unroll
    for (int i = 0; i < 4; i++)
        wuT[(size_t)(d0 + ty + 8 * i) * EE + e0 + tx] = f2bf(tile[tx][ty + 8 * i]);
}

// ---------------- generic bf16 GEMM  C = A(MxK) * B(NxK)^T ----------------
// 128x128 tile, BK=64, 256 threads (4 waves, 2x2 of 64x64 wave tiles,
// each wave 4x4 of 16x16x32 MFMA). XOR-swizzled LDS (slot = kchunk ^ (row&7)).
// EPI: 1 = relu(acc)*scale[col], write bf16 (C tile)   scale = w (pre-offset)
//      2 = atomicAdd into fp32 out (qh accumulate + split-K GEMM2)
template <int EPI>
__global__ __launch_bounds__(256, 2) void gemm_bt(
    const unsigned short* __restrict__ A, int lda,
    const unsigned short* __restrict__ B, int ldb,
    int kIters,
    float* __restrict__ outF, unsigned short* __restrict__ outB, int ldc,
    const float* __restrict__ scale) {
    __shared__ __align__(16) unsigned short As[128 * 64];
    __shared__ __align__(16) unsigned short Bs[128 * 64];

    int tid = threadIdx.x;
    int lane = tid & 63, wave = tid >> 6;
    int wm = (wave >> 1) * 64, wn = (wave & 1) * 64;
    int row0 = blockIdx.x * 128, col0 = blockIdx.y * 128;
    int k00 = blockIdx.z * kIters * 64;      // split-K offset (z==0 otherwise)

    int rr = tid >> 3;
    int ss = tid & 7;
    int kb = ss ^ (rr & 7);
    const unsigned short* Ab = A + (size_t)(row0 + rr) * lda + k00 + kb * 8;
    const unsigned short* Bb = B + (size_t)(col0 + rr) * ldb + k00 + kb * 8;

    f32x4 acc[4][4];
#pragma unroll
    for (int i = 0; i < 4; i++)
#pragma unroll
        for (int j = 0; j < 4; j++) acc[i][j] = 0.f;

    for (int kt = 0; kt < kIters; ++kt) {
        uint4 ra[4], rb[4];
#pragma unroll
        for (int i = 0; i < 4; i++) {
            ra[i] = *(const uint4*)(Ab + (size_t)(32 * i) * lda + kt * 64);
            rb[i] = *(const uint4*)(Bb + (size_t)(32 * i) * ldb + kt * 64);
        }
        __syncthreads();
#pragma unroll
        for (int i = 0; i < 4; i++) {
            ((uint4*)As)[i * 256 + tid] = ra[i];
            ((uint4*)Bs)[i * 256 + tid] = rb[i];
        }
        __syncthreads();
#pragma unroll
        for (int ks = 0; ks < 2; ks++) {
            bf16x8 af[4], bfr[4];
#pragma unroll
            for (int i = 0; i < 4; i++) {
                int m = wm + i * 16 + (lane & 15);
                int kq = ks * 4 + (lane >> 4);
                af[i]  = *(const bf16x8*)(As + m * 64 + ((kq ^ (m & 7)) * 8));
                int n = wn + i * 16 + (lane & 15);
                bfr[i] = *(const bf16x8*)(Bs + n * 64 + ((kq ^ (n & 7)) * 8));
            }
#pragma unroll
            for (int i = 0; i < 4; i++)
#pragma unroll
                for (int j = 0; j < 4; j++)
                    acc[i][j] = __builtin_amdgcn_mfma_f32_16x16x32_bf16(
                        af[i], bfr[j], acc[i][j], 0, 0, 0);
        }
    }

    // epilogue: D[row=(lane>>4)*4+r][col=lane&15] per 16x16 tile (m89-verified)
#pragma unroll
    for (int i = 0; i < 4; i++) {
        int rbase = row0 + wm + i * 16 + (lane >> 4) * 4;
#pragma unroll
        for (int j = 0; j < 4; j++) {
            int c = col0 + wn + j * 16 + (lane & 15);
#pragma unroll
            for (int r2 = 0; r2 < 4; r2++) {
                float v = acc[i][j][r2];
                int row = rbase + r2;
                if (EPI == 1) {
                    outB[(size_t)row * ldc + c] = f2bf(fmaxf(v, 0.f) * scale[c]);
                } else {
                    atomicAdd(&outF[(size_t)row * ldc + c], v);
                }
            }
        }
    }
}

// ---------------- fused scoring + twin top-16 + combo top-16 + softmax ----
__global__ __launch_bounds__(256) void score_topk(
    const float* __restrict__ qh, const float* __restrict__ bq,
    const float* __restrict__ keys, float* __restrict__ w) {
    int nt = blockIdx.x, h = blockIdx.y;
    int tid = threadIdx.x;
    __shared__ __align__(16) float q[128];
    __shared__ float s1[EXP], s2[EXP];
    __shared__ float t1v[16], t2v[16];
    __shared__ int   t1i[16], t2i[16];
    __shared__ float selv[16];
    __shared__ int   seli[16];

    if (tid < 128) q[tid] = qh[nt * HDK + h * DKH + tid] + bq[h * DKH + tid];
    __syncthreads();

    {   // s1[e], s2[e] fp32 dots over 64
        int e = tid;
        const float4* k1 = (const float4*)(keys + ((size_t)(h * 2 + 0) * EXP + e) * HALFD);
        const float4* k2 = (const float4*)(keys + ((size_t)(h * 2 + 1) * EXP + e) * HALFD);
        const float4* q1 = (const float4*)q;
        const float4* q2 = (const float4*)(q + 64);
        float a1 = 0.f, a2 = 0.f;
#pragma unroll
        for (int c = 0; c < 16; c++) {
            float4 ka = k1[c], qa = q1[c];
            a1 += ka.x * qa.x + ka.y * qa.y + ka.z * qa.z + ka.w * qa.w;
            float4 kb = k2[c], qb = q2[c];
            a2 += kb.x * qb.x + kb.y * qb.y + kb.z * qb.z + kb.w * qb.w;
        }
        s1[e] = a1; s2[e] = a2;
    }
    __syncthreads();

    int lane = tid & 63;
    if (tid < 128) {  // wave0 -> top16(s1), wave1 -> top16(s2)
        float* s = (tid < 64) ? s1 : s2;
        float* tv = (tid < 64) ? t1v : t2v;
        int*   ti = (tid < 64) ? t1i : t2i;
        float v[4]; int ix[4];
#pragma unroll
        for (int j = 0; j < 4; j++) { v[j] = s[lane + 64 * j]; ix[j] = lane + 64 * j; }
        for (int it = 0; it < 16; it++) {
            float bv = v[0]; int bi = ix[0];
#pragma unroll
            for (int j = 1; j < 4; j++)
                if (v[j] > bv || (v[j] == bv && ix[j] < bi)) { bv = v[j]; bi = ix[j]; }
#pragma unroll
            for (int o = 32; o > 0; o >>= 1) {
                float ov = __shfl_xor(bv, o, 64);
                int   oi = __shfl_xor(bi, o, 64);
                if (ov > bv || (ov == bv && oi < bi)) { bv = ov; bi = oi; }
            }
            if (lane == 0) { tv[it] = bv; ti[it] = bi; }
#pragma unroll
            for (int j = 0; j < 4; j++) if (ix[j] == bi) v[j] = -__builtin_inff();
        }
    }
    __syncthreads();

    if (tid < 64) {  // wave0: top-16 of the 256 pair-sums, then softmax -> w
        float v[4]; int ix[4];
#pragma unroll
        for (int j = 0; j < 4; j++) {
            int qq = lane + 64 * j;
            v[j] = t1v[qq >> 4] + t2v[qq & 15];
            ix[j] = qq;
        }
        for (int it = 0; it < 16; it++) {
            float bv = v[0]; int bi = ix[0];
#pragma unroll
            for (int j = 1; j < 4; j++)
                if (v[j] > bv || (v[j] == bv && ix[j] < bi)) { bv = v[j]; bi = ix[j]; }
#pragma unroll
            for (int o = 32; o > 0; o >>= 1) {
                float ov = __shfl_xor(bv, o, 64);
                int   oi = __shfl_xor(bi, o, 64);
                if (ov > bv || (ov == bv && oi < bi)) { bv = ov; bi = oi; }
            }
            if (lane == 0) {
                selv[it] = bv;
                seli[it] = t1i[bi >> 4] * EXP + t2i[bi & 15];
            }
#pragma unroll
            for (int j = 0; j < 4; j++) if (ix[j] == bi) v[j] = -__builtin_inff();
        }
        if (lane < 16) {
            float val = selv[lane];
            float mx = val;
#pragma unroll
            for (int o = 1; o < 16; o <<= 1) mx = fmaxf(mx, __shfl_xor(mx, o, 64));
            float ex = __expf(val - mx);
            float sm = ex;
#pragma unroll
            for (int o = 1; o < 16; o <<= 1) sm += __shfl_xor(sm, o, 64);
            atomicAdd(&w[seli[lane]], ex / sm);
        }
    }
}

// ---------------- launch ----------------
extern "C" void kernel_launch(void* const* d_in, const int* in_sizes, int n_in,
                              void* d_out, int out_size, void* d_ws, size_t ws_size,
                              hipStream_t stream) {
    const float* queries = (const float*)d_in[0];   // (2,512,512)
    const float* Wq      = (const float*)d_in[1];   // (1024,512)
    const float* bq      = (const float*)d_in[2];   // (1024)
    const float* keys    = (const float*)d_in[3];   // (8,2,256,64)
    const float* wd      = (const float*)d_in[4];   // (65536,512)
    const float* wu      = (const float*)d_in[5];   // (65536,512)
    float* out = (float*)d_out;                     // (2,512,512) fp32

    // workspace layout (~199 MB total)
    uint8_t* ws = (uint8_t*)d_ws;
    unsigned short* Qb  = (unsigned short*)(ws);                          // 1 MB
    unsigned short* Wqb = (unsigned short*)(ws + (size_t)(1u) * 1048576); // 1 MB
    unsigned short* Wdb = (unsigned short*)(ws + (size_t)(2u) * 1048576); // 64 MB
    unsigned short* WuT = (unsigned short*)(ws + (size_t)(66u) * 1048576);// 64 MB
    float* qh = (float*)(ws + (size_t)(130u) * 1048576);                  // 4 MB
    float* w  = (float*)(ws + (size_t)(134u) * 1048576);                  // 256 KB
    unsigned short* Cb = (unsigned short*)(ws + (size_t)(135u) * 1048576);// 64 MB
    // lo-parts alias the (not-yet-used) C buffer
    unsigned short* Qlo  = Cb;                 // 1 MB
    unsigned short* Wqlo = Cb + 524288;        // 1 MB

    hipMemsetAsync(w, 0, EE * sizeof(float), stream);
    hipMemsetAsync(qh, 0, (size_t)NTOK * HDK * sizeof(float), stream);
    hipMemsetAsync(d_out, 0, (size_t)out_size * sizeof(float), stream);

    cvt_bf16_hilo<<<512, 256, 0, stream>>>(queries, Qb, Qlo, 131072);
    cvt_bf16_hilo<<<512, 256, 0, stream>>>(Wq, Wqb, Wqlo, 131072);
    cvt_bf16<<<16384, 256, 0, stream>>>(wd, Wdb, 4194304);
    transpose_wu<<<dim3(16, 2048), dim3(32, 8), 0, stream>>>(wu, WuT);

    // qh = Q @ Wq^T  in ~fp32 via bf16 hi/lo 3-term expansion (bias added later)
    gemm_bt<2><<<dim3(8, 8, 1), 256, 0, stream>>>(Qb,  DIM, Wqb,  DIM, 8,
                                                  qh, nullptr, HDK, nullptr);
    gemm_bt<2><<<dim3(8, 8, 1), 256, 0, stream>>>(Qb,  DIM, Wqlo, DIM, 8,
                                                  qh, nullptr, HDK, nullptr);
    gemm_bt<2><<<dim3(8, 8, 1), 256, 0, stream>>>(Qlo, DIM, Wqb,  DIM, 8,
                                                  qh, nullptr, HDK, nullptr);

    // scores, top-k, softmax -> w[e]
    score_topk<<<dim3(NTOK, NH), 256, 0, stream>>>(qh, bq, keys, w);

    // big GEMMs, split into 2 e-halves to reuse one 64 MB C buffer
    for (int sp = 0; sp < 2; sp++) {
        const unsigned short* Bp = Wdb + (size_t)sp * 32768 * DIM;
        // C[t,e] = relu(Q.wd[e]) * w[e]   (M=1024, N=32768, K=512)
        gemm_bt<1><<<dim3(8, 256, 1), 256, 0, stream>>>(
            Qb, DIM, Bp, DIM, 8, nullptr, Cb, 32768, w + (size_t)sp * 32768);
        // out[t,d] += C[t,:] . WuT[d,:]   (M=1024, N=512, K=32768, splitK=16)
        gemm_bt<2><<<dim3(8, 4, 16), 256, 0, stream>>>(
            Cb, 32768, WuT + (size_t)sp * 32768, EE, 32, out, nullptr, DIM, nullptr);
    }
}

// Round 3
// 705.891 us; speedup vs baseline: 1.9339x; 1.9339x over previous
//
#include <hip/hip_runtime.h>
#include <stdint.h>

// Problem constants
#define NTOK 1024          // N*T
#define DIM  512           // D
#define NH   8             // H
#define DKH  128           // DK
#define HALFD 64           // DK/2
#define EXP  256           // E
#define EE   65536         // E*E
#define HDK  1024          // H*DK

typedef short bf16x8 __attribute__((ext_vector_type(8)));
typedef float f32x4  __attribute__((ext_vector_type(4)));

__device__ __forceinline__ unsigned short f2bf(float f) {
    unsigned u = __float_as_uint(f);
    u += 0x7fff + ((u >> 16) & 1);     // round-to-nearest-even
    return (unsigned short)(u >> 16);
}
__device__ __forceinline__ float bf2f(unsigned short h) {
    return __uint_as_float((unsigned)h << 16);
}

// async global->LDS, 16B per lane (m97 ladder step)
__device__ __forceinline__ void gload16(const unsigned short* g, unsigned short* l) {
    __builtin_amdgcn_global_load_lds(
        (const __attribute__((address_space(1))) void*)g,
        (__attribute__((address_space(3))) void*)l, 16, 0, 0);
}

// ---------------- fp32 -> bf16 convert (8 elems/thread) ----------------
__global__ void cvt_bf16(const float* __restrict__ src,
                         unsigned short* __restrict__ dst, int n8) {
    int i = blockIdx.x * blockDim.x + threadIdx.x;
    if (i >= n8) return;
    const float4* s4 = (const float4*)src;
    float4 a = s4[2 * i], b = s4[2 * i + 1];
    union { unsigned short u[8]; uint4 v; } r;
    r.u[0] = f2bf(a.x); r.u[1] = f2bf(a.y); r.u[2] = f2bf(a.z); r.u[3] = f2bf(a.w);
    r.u[4] = f2bf(b.x); r.u[5] = f2bf(b.y); r.u[6] = f2bf(b.z); r.u[7] = f2bf(b.w);
    ((uint4*)dst)[i] = r.v;
}

// ------- fp32 (1024x512) -> K-concat hi/lo pack (1024x1536 bf16) -------
// MODE 0 (Q):  dst row = [hi | hi | lo]
// MODE 1 (Wq): dst row = [hi | lo | hi]
// Sum over K=1536 of Qcat.Wqcat^T = hi.hi + hi.lo + lo.hi  (~fp32 qh)
template <int MODE>
__global__ void cvt_pack(const float* __restrict__ src,
                         unsigned short* __restrict__ dst) {
    int i = blockIdx.x * blockDim.x + threadIdx.x;  // float4 idx over 1024x512
    if (i >= 131072) return;
    int r = i >> 7, c4 = i & 127;
    float4 a = ((const float4*)src)[i];
    union { unsigned short u[4]; uint2 v; } rh, rl;
    float x[4] = {a.x, a.y, a.z, a.w};
#pragma unroll
    for (int j = 0; j < 4; j++) {
        unsigned short h = f2bf(x[j]);
        rh.u[j] = h;
        rl.u[j] = f2bf(x[j] - bf2f(h));
    }
    uint2* A2 = (uint2*)dst;                 // row stride 1536 shorts = 384 uint2
    A2[r * 384 + c4] = rh.v;
    A2[r * 384 + 128 + c4] = (MODE == 0) ? rh.v : rl.v;
    A2[r * 384 + 256 + c4] = (MODE == 0) ? rl.v : rh.v;
}

// ------- w_up half (32768 x 512) fp32 -> WuTh (512 x 32768) bf16 -------
__global__ void transpose_wu(const float* __restrict__ wu,
                             unsigned short* __restrict__ wuT, int e0base) {
    __shared__ float tile[32][33];
    int d0 = blockIdx.x * 32;
    int eb = blockIdx.y * 32;          // within-half e offset
    int tx = threadIdx.x, ty = threadIdx.y;
#pragma unroll
    for (int i = 0; i < 4; i++)
        tile[ty + 8 * i][tx] = wu[(size_t)(e0base + eb + ty + 8 * i) * DIM + d0 + tx];
    __syncthreads();
#pragma unroll
    for (int i = 0; i < 4; i++)
        wuT[(size_t)(d0 + ty + 8 * i) * 32768 + eb + tx] = f2bf(tile[tx][ty + 8 * i]);
}

// ---------------- generic bf16 GEMM  C = A(MxK) * B(NxK)^T ----------------
// 128x128 tile, BK=64, 256 threads (4 waves, 2x2 of 64x64 wave tiles,
// each wave 4x4 of 16x16x32 MFMA). XOR source-swizzle (kchunk = slot ^ (row&7))
// + global_load_lds width-16 staging (m97 structure).
// EPI: 0 = plain store fp32 (qh)
//      1 = relu(acc)*scale[col], store bf16 (C tile); scale = w (pre-offset)
//      4 = store fp32 partial at slice blockIdx.z (split-K, no atomics)
template <int EPI>
__global__ __launch_bounds__(256, 4) void gemm_bt(
    const unsigned short* __restrict__ A, int lda,
    const unsigned short* __restrict__ B, int ldb,
    int kIters,
    float* __restrict__ outF, unsigned short* __restrict__ outB, int ldc,
    const float* __restrict__ scale, size_t sliceStride) {
    __shared__ __align__(16) unsigned short As[128 * 64];
    __shared__ __align__(16) unsigned short Bs[128 * 64];

    int tid = threadIdx.x;
    int lane = tid & 63, wave = tid >> 6;
    int wm = (wave >> 1) * 64, wn = (wave & 1) * 64;
    int row0 = blockIdx.x * 128, col0 = blockIdx.y * 128;
    size_t k00 = (size_t)blockIdx.z * kIters * 64;   // split-K offset

    int rr = tid >> 3;
    int ss = tid & 7;
    int kb = ss ^ (rr & 7);
    const unsigned short* Ab = A + (size_t)(row0 + rr) * lda + k00 + kb * 8;
    const unsigned short* Bb = B + (size_t)(col0 + rr) * ldb + k00 + kb * 8;
    unsigned short* Asw = As + (size_t)tid * 8;      // lane-linear LDS dest
    unsigned short* Bsw = Bs + (size_t)tid * 8;

    f32x4 acc[4][4];
#pragma unroll
    for (int i = 0; i < 4; i++)
#pragma unroll
        for (int j = 0; j < 4; j++) acc[i][j] = 0.f;

    for (int kt = 0; kt < kIters; ++kt) {
        __syncthreads();                              // LDS consumers done
#pragma unroll
        for (int i = 0; i < 4; i++)
            gload16(Ab + (size_t)(32 * i) * lda + kt * 64, Asw + i * 2048);
#pragma unroll
        for (int i = 0; i < 4; i++)
            gload16(Bb + (size_t)(32 * i) * ldb + kt * 64, Bsw + i * 2048);
        __syncthreads();                              // vmcnt(0) drained here
#pragma unroll
        for (int ks = 0; ks < 2; ks++) {
            bf16x8 af[4], bfr[4];
#pragma unroll
            for (int i = 0; i < 4; i++) {
                int m = wm + i * 16 + (lane & 15);
                int kq = ks * 4 + (lane >> 4);
                af[i]  = *(const bf16x8*)(As + m * 64 + ((kq ^ (m & 7)) * 8));
                int n = wn + i * 16 + (lane & 15);
                bfr[i] = *(const bf16x8*)(Bs + n * 64 + ((kq ^ (n & 7)) * 8));
            }
#pragma unroll
            for (int i = 0; i < 4; i++)
#pragma unroll
                for (int j = 0; j < 4; j++)
                    acc[i][j] = __builtin_amdgcn_mfma_f32_16x16x32_bf16(
                        af[i], bfr[j], acc[i][j], 0, 0, 0);
        }
    }

    // epilogue: D[row=(lane>>4)*4+r][col=lane&15] per 16x16 tile (m89-verified)
#pragma unroll
    for (int i = 0; i < 4; i++) {
        int rbase = row0 + wm + i * 16 + (lane >> 4) * 4;
#pragma unroll
        for (int j = 0; j < 4; j++) {
            int c = col0 + wn + j * 16 + (lane & 15);
#pragma unroll
            for (int r2 = 0; r2 < 4; r2++) {
                float v = acc[i][j][r2];
                int row = rbase + r2;
                if (EPI == 0) {
                    outF[(size_t)row * ldc + c] = v;
                } else if (EPI == 1) {
                    outB[(size_t)row * ldc + c] = f2bf(fmaxf(v, 0.f) * scale[c]);
                } else {  // EPI == 4
                    outF[(size_t)blockIdx.z * sliceStride + (size_t)row * ldc + c] = v;
                }
            }
        }
    }
}

// ---------------- sum 16 split-K partial slices -> out ----------------
__global__ void reduce_part(const float* __restrict__ part,
                            float* __restrict__ out) {
    int i = blockIdx.x * blockDim.x + threadIdx.x;   // float4 idx, 131072 total
    const float4* p4 = (const float4*)part;
    float4 s = p4[i];
#pragma unroll
    for (int sl = 1; sl < 16; sl++) {
        float4 t = p4[(size_t)sl * 131072 + i];
        s.x += t.x; s.y += t.y; s.z += t.z; s.w += t.w;
    }
    ((float4*)out)[i] = s;
}

// ---------------- fused scoring + twin top-16 + combo top-16 + softmax ----
__global__ __launch_bounds__(256) void score_topk(
    const float* __restrict__ qh, const float* __restrict__ bq,
    const float* __restrict__ keys, float* __restrict__ w) {
    int nt = blockIdx.x, h = blockIdx.y;
    int tid = threadIdx.x;
    __shared__ __align__(16) float q[128];
    __shared__ float s1[EXP], s2[EXP];
    __shared__ float t1v[16], t2v[16];
    __shared__ int   t1i[16], t2i[16];
    __shared__ float selv[16];
    __shared__ int   seli[16];

    if (tid < 128) q[tid] = qh[nt * HDK + h * DKH + tid] + bq[h * DKH + tid];
    __syncthreads();

    {   // s1[e], s2[e] fp32 dots over 64
        int e = tid;
        const float4* k1 = (const float4*)(keys + ((size_t)(h * 2 + 0) * EXP + e) * HALFD);
        const float4* k2 = (const float4*)(keys + ((size_t)(h * 2 + 1) * EXP + e) * HALFD);
        const float4* q1 = (const float4*)q;
        const float4* q2 = (const float4*)(q + 64);
        float a1 = 0.f, a2 = 0.f;
#pragma unroll
        for (int c = 0; c < 16; c++) {
            float4 ka = k1[c], qa = q1[c];
            a1 += ka.x * qa.x + ka.y * qa.y + ka.z * qa.z + ka.w * qa.w;
            float4 kb = k2[c], qb = q2[c];
            a2 += kb.x * qb.x + kb.y * qb.y + kb.z * qb.z + kb.w * qb.w;
        }
        s1[e] = a1; s2[e] = a2;
    }
    __syncthreads();

    int lane = tid & 63;
    if (tid < 128) {  // wave0 -> top16(s1), wave1 -> top16(s2)
        float* s = (tid < 64) ? s1 : s2;
        float* tv = (tid < 64) ? t1v : t2v;
        int*   ti = (tid < 64) ? t1i : t2i;
        float v[4]; int ix[4];
#pragma unroll
        for (int j = 0; j < 4; j++) { v[j] = s[lane + 64 * j]; ix[j] = lane + 64 * j; }
        for (int it = 0; it < 16; it++) {
            float bv = v[0]; int bi = ix[0];
#pragma unroll
            for (int j = 1; j < 4; j++)
                if (v[j] > bv || (v[j] == bv && ix[j] < bi)) { bv = v[j]; bi = ix[j]; }
#pragma unroll
            for (int o = 32; o > 0; o >>= 1) {
                float ov = __shfl_xor(bv, o, 64);
                int   oi = __shfl_xor(bi, o, 64);
                if (ov > bv || (ov == bv && oi < bi)) { bv = ov; bi = oi; }
            }
            if (lane == 0) { tv[it] = bv; ti[it] = bi; }
#pragma unroll
            for (int j = 0; j < 4; j++) if (ix[j] == bi) v[j] = -__builtin_inff();
        }
    }
    __syncthreads();

    if (tid < 64) {  // wave0: top-16 of the 256 pair-sums, then softmax -> w
        float v[4]; int ix[4];
#pragma unroll
        for (int j = 0; j < 4; j++) {
            int qq = lane + 64 * j;
            v[j] = t1v[qq >> 4] + t2v[qq & 15];
            ix[j] = qq;
        }
        for (int it = 0; it < 16; it++) {
            float bv = v[0]; int bi = ix[0];
#pragma unroll
            for (int j = 1; j < 4; j++)
                if (v[j] > bv || (v[j] == bv && ix[j] < bi)) { bv = v[j]; bi = ix[j]; }
#pragma unroll
            for (int o = 32; o > 0; o >>= 1) {
                float ov = __shfl_xor(bv, o, 64);
                int   oi = __shfl_xor(bi, o, 64);
                if (ov > bv || (ov == bv && oi < bi)) { bv = ov; bi = oi; }
            }
            if (lane == 0) {
                selv[it] = bv;
                seli[it] = t1i[bi >> 4] * EXP + t2i[bi & 15];
            }
#pragma unroll
            for (int j = 0; j < 4; j++) if (ix[j] == bi) v[j] = -__builtin_inff();
        }
        if (lane < 16) {
            float val = selv[lane];
            float mx = val;
#pragma unroll
            for (int o = 1; o < 16; o <<= 1) mx = fmaxf(mx, __shfl_xor(mx, o, 64));
            float ex = __expf(val - mx);
            float sm = ex;
#pragma unroll
            for (int o = 1; o < 16; o <<= 1) sm += __shfl_xor(sm, o, 64);
            atomicAdd(&w[seli[lane]], ex / sm);
        }
    }
}

// ---------------- launch ----------------
extern "C" void kernel_launch(void* const* d_in, const int* in_sizes, int n_in,
                              void* d_out, int out_size, void* d_ws, size_t ws_size,
                              hipStream_t stream) {
    const float* queries = (const float*)d_in[0];   // (2,512,512)
    const float* Wq      = (const float*)d_in[1];   // (1024,512)
    const float* bq      = (const float*)d_in[2];   // (1024)
    const float* keys    = (const float*)d_in[3];   // (8,2,256,64)
    const float* wd      = (const float*)d_in[4];   // (65536,512)
    const float* wu      = (const float*)d_in[5];   // (65536,512)
    float* out = (float*)d_out;                     // (2,512,512) fp32

    // workspace layout (171 MB total)
    uint8_t* ws = (uint8_t*)d_ws;
    const size_t MB = 1048576;
    unsigned short* Qcat  = (unsigned short*)(ws);            // 3 MB  (1024x1536)
    unsigned short* Wqcat = (unsigned short*)(ws + 3 * MB);   // 3 MB  (1024x1536)
    float*          qh    = (float*)(ws + 6 * MB);            // 4 MB  (1024x1024)
    float*          w     = (float*)(ws + 10 * MB);           // 256 KB
    unsigned short* Wdh   = (unsigned short*)(ws + 11 * MB);  // 32 MB (32768x512)
    unsigned short* WuTh  = (unsigned short*)(ws + 43 * MB);  // 32 MB (512x32768)
    unsigned short* Cb    = (unsigned short*)(ws + 75 * MB);  // 64 MB (1024x32768)
    float*          Ppart = (float*)(ws + 139 * MB);          // 32 MB (16 x 1024x512)

    hipMemsetAsync(w, 0, EE * sizeof(float), stream);

    cvt_pack<0><<<512, 256, 0, stream>>>(queries, Qcat);
    cvt_pack<1><<<512, 256, 0, stream>>>(Wq, Wqcat);

    // qh = Q @ Wq^T in ~fp32 via single K=1536 concat GEMM (bias in score_topk)
    gemm_bt<0><<<dim3(8, 8, 1), 256, 0, stream>>>(
        Qcat, 1536, Wqcat, 1536, 24, qh, nullptr, HDK, nullptr, 0);

    // scores, top-k, softmax -> w[e]
    score_topk<<<dim3(NTOK, NH), 256, 0, stream>>>(qh, bq, keys, w);

    // big GEMMs per e-half; converts reuse 32 MB buffers inside the loop
    for (int sp = 0; sp < 2; sp++) {
        cvt_bf16<<<8192, 256, 0, stream>>>(wd + (size_t)sp * 16777216, Wdh, 2097152);
        // C[t,e] = relu(Q . wd[e]) * w[e]   (M=1024, N=32768, K=512)
        gemm_bt<1><<<dim3(8, 256, 1), 256, 0, stream>>>(
            Qcat, 1536, Wdh, DIM, 8, nullptr, Cb, 32768, w + (size_t)sp * 32768, 0);
        transpose_wu<<<dim3(16, 1024), dim3(32, 8), 0, stream>>>(wu, WuTh, sp * 32768);
        // partial[z][t,d] = C[t, z-slice] . WuT[d, z-slice]  (split-K=8, plain stores)
        gemm_bt<4><<<dim3(8, 4, 8), 256, 0, stream>>>(
            Cb, 32768, WuTh, 32768, 64, Ppart + (size_t)sp * 8 * 524288, nullptr,
            DIM, nullptr, 524288);
    }
    // out = sum of 16 partial slices
    reduce_part<<<512, 256, 0, stream>>>(Ppart, out);
}

// Round 4
// 704.540 us; speedup vs baseline: 1.9376x; 1.0019x over previous
//
#include <hip/hip_runtime.h>
#include <stdint.h>

// Problem constants
#define NTOK 1024          // N*T
#define DIM  512           // D
#define NH   8             // H
#define DKH  128           // DK
#define HALFD 64           // DK/2
#define EXP  256           // E
#define EE   65536         // E*E
#define HDK  1024          // H*DK

typedef short bf16x8 __attribute__((ext_vector_type(8)));
typedef float f32x4  __attribute__((ext_vector_type(4)));

__device__ __forceinline__ unsigned short f2bf(float f) {
    unsigned u = __float_as_uint(f);
    u += 0x7fff + ((u >> 16) & 1);     // round-to-nearest-even
    return (unsigned short)(u >> 16);
}
__device__ __forceinline__ float bf2f(unsigned short h) {
    return __uint_as_float((unsigned)h << 16);
}

// sortable key: higher float -> higher key; ties -> lower index higher key
// (matches lax.top_k stable ordering exactly)
__device__ __forceinline__ unsigned long long mkkey(float x, int idx) {
    unsigned u = __float_as_uint(x);
    unsigned mu = u ^ ((unsigned)((int)u >> 31) | 0x80000000u);
    return ((unsigned long long)mu << 32) | (unsigned)(255 - idx);
}

// async global->LDS, 16B per lane (m97 ladder step)
__device__ __forceinline__ void gload16(const unsigned short* g, unsigned short* l) {
    __builtin_amdgcn_global_load_lds(
        (const __attribute__((address_space(1))) void*)g,
        (__attribute__((address_space(3))) void*)l, 16, 0, 0);
}

// ---------------- fp32 -> bf16 convert (8 elems/thread) ----------------
__global__ void cvt_bf16(const float* __restrict__ src,
                         unsigned short* __restrict__ dst, int n8) {
    int i = blockIdx.x * blockDim.x + threadIdx.x;
    if (i >= n8) return;
    const float4* s4 = (const float4*)src;
    float4 a = s4[2 * i], b = s4[2 * i + 1];
    union { unsigned short u[8]; uint4 v; } r;
    r.u[0] = f2bf(a.x); r.u[1] = f2bf(a.y); r.u[2] = f2bf(a.z); r.u[3] = f2bf(a.w);
    r.u[4] = f2bf(b.x); r.u[5] = f2bf(b.y); r.u[6] = f2bf(b.z); r.u[7] = f2bf(b.w);
    ((uint4*)dst)[i] = r.v;
}

// ------- fp32 (1024x512) -> K-concat hi/lo pack (1024x1536 bf16) -------
// MODE 0 (Q):  dst row = [hi | hi | lo]
// MODE 1 (Wq): dst row = [hi | lo | hi]
template <int MODE>
__global__ void cvt_pack(const float* __restrict__ src,
                         unsigned short* __restrict__ dst) {
    int i = blockIdx.x * blockDim.x + threadIdx.x;  // float4 idx over 1024x512
    if (i >= 131072) return;
    int r = i >> 7, c4 = i & 127;
    float4 a = ((const float4*)src)[i];
    union { unsigned short u[4]; uint2 v; } rh, rl;
    float x[4] = {a.x, a.y, a.z, a.w};
#pragma unroll
    for (int j = 0; j < 4; j++) {
        unsigned short h = f2bf(x[j]);
        rh.u[j] = h;
        rl.u[j] = f2bf(x[j] - bf2f(h));
    }
    uint2* A2 = (uint2*)dst;                 // row stride 1536 shorts = 384 uint2
    A2[r * 384 + c4] = rh.v;
    A2[r * 384 + 128 + c4] = (MODE == 0) ? rh.v : rl.v;
    A2[r * 384 + 256 + c4] = (MODE == 0) ? rl.v : rh.v;
}

// ------- w_up half (32768 x 512) fp32 -> WuTh (512 x 32768) bf16 -------
__global__ void transpose_wu(const float* __restrict__ wu,
                             unsigned short* __restrict__ wuT, int e0base) {
    __shared__ float tile[32][33];
    int d0 = blockIdx.x * 32;
    int eb = blockIdx.y * 32;          // within-half e offset
    int tx = threadIdx.x, ty = threadIdx.y;
#pragma unroll
    for (int i = 0; i < 4; i++)
        tile[ty + 8 * i][tx] = wu[(size_t)(e0base + eb + ty + 8 * i) * DIM + d0 + tx];
    __syncthreads();
#pragma unroll
    for (int i = 0; i < 4; i++)
        wuT[(size_t)(d0 + ty + 8 * i) * 32768 + eb + tx] = f2bf(tile[tx][ty + 8 * i]);
}

// ---------------- generic bf16 GEMM  C = A(MxK) * B(NxK)^T ----------------
// 128x128 tile, BK=64, 256 threads. global_load_lds width-16 staging,
// XOR source-swizzle (kchunk = slot ^ (row&7)) for conflict-free ds_read_b128.
// EPI: 0 = plain store fp32 (qh)
//      1 = relu(acc)*scale[col], store bf16 (C tile); scale = w (pre-offset)
//      4 = store bf16 partial at slice blockIdx.z (split-K, no atomics)
template <int EPI>
__global__ __launch_bounds__(256, 4) void gemm_bt(
    const unsigned short* __restrict__ A, int lda,
    const unsigned short* __restrict__ B, int ldb,
    int kIters,
    float* __restrict__ outF, unsigned short* __restrict__ outB, int ldc,
    const float* __restrict__ scale, size_t sliceStride) {
    __shared__ __align__(16) unsigned short As[128 * 64];
    __shared__ __align__(16) unsigned short Bs[128 * 64];

    int tid = threadIdx.x;
    int lane = tid & 63, wave = tid >> 6;
    int wm = (wave >> 1) * 64, wn = (wave & 1) * 64;
    int row0 = blockIdx.x * 128, col0 = blockIdx.y * 128;
    size_t k00 = (size_t)blockIdx.z * kIters * 64;   // split-K offset

    int rr = tid >> 3;
    int ss = tid & 7;
    int kb = ss ^ (rr & 7);
    const unsigned short* Ab = A + (size_t)(row0 + rr) * lda + k00 + kb * 8;
    const unsigned short* Bb = B + (size_t)(col0 + rr) * ldb + k00 + kb * 8;
    unsigned short* Asw = As + (size_t)tid * 8;      // lane-linear LDS dest
    unsigned short* Bsw = Bs + (size_t)tid * 8;

    f32x4 acc[4][4];
#pragma unroll
    for (int i = 0; i < 4; i++)
#pragma unroll
        for (int j = 0; j < 4; j++) acc[i][j] = 0.f;

    for (int kt = 0; kt < kIters; ++kt) {
        __syncthreads();                              // LDS consumers done
#pragma unroll
        for (int i = 0; i < 4; i++)
            gload16(Ab + (size_t)(32 * i) * lda + kt * 64, Asw + i * 2048);
#pragma unroll
        for (int i = 0; i < 4; i++)
            gload16(Bb + (size_t)(32 * i) * ldb + kt * 64, Bsw + i * 2048);
        __syncthreads();                              // vmcnt(0) drained here
#pragma unroll
        for (int ks = 0; ks < 2; ks++) {
            bf16x8 af[4], bfr[4];
#pragma unroll
            for (int i = 0; i < 4; i++) {
                int m = wm + i * 16 + (lane & 15);
                int kq = ks * 4 + (lane >> 4);
                af[i]  = *(const bf16x8*)(As + m * 64 + ((kq ^ (m & 7)) * 8));
                int n = wn + i * 16 + (lane & 15);
                bfr[i] = *(const bf16x8*)(Bs + n * 64 + ((kq ^ (n & 7)) * 8));
            }
#pragma unroll
            for (int i = 0; i < 4; i++)
#pragma unroll
                for (int j = 0; j < 4; j++)
                    acc[i][j] = __builtin_amdgcn_mfma_f32_16x16x32_bf16(
                        af[i], bfr[j], acc[i][j], 0, 0, 0);
        }
    }

    // epilogue: D[row=(lane>>4)*4+r][col=lane&15] per 16x16 tile (m89-verified)
#pragma unroll
    for (int i = 0; i < 4; i++) {
        int rbase = row0 + wm + i * 16 + (lane >> 4) * 4;
#pragma unroll
        for (int j = 0; j < 4; j++) {
            int c = col0 + wn + j * 16 + (lane & 15);
#pragma unroll
            for (int r2 = 0; r2 < 4; r2++) {
                float v = acc[i][j][r2];
                int row = rbase + r2;
                if (EPI == 0) {
                    outF[(size_t)row * ldc + c] = v;
                } else if (EPI == 1) {
                    outB[(size_t)row * ldc + c] = f2bf(fmaxf(v, 0.f) * scale[c]);
                } else {  // EPI == 4: bf16 split-K partial
                    outB[(size_t)blockIdx.z * sliceStride + (size_t)row * ldc + c] =
                        f2bf(v);
                }
            }
        }
    }
}

// ---------------- sum 64 bf16 split-K partial slices -> out ----------------
__global__ void reduce_part(const unsigned short* __restrict__ part,
                            float* __restrict__ out) {
    int i = blockIdx.x * blockDim.x + threadIdx.x;   // 8-elem group, 65536 total
    const uint4* p4 = (const uint4*)part;            // 8 bf16 per uint4
    float s[8];
#pragma unroll
    for (int j = 0; j < 8; j++) s[j] = 0.f;
    for (int sl = 0; sl < 64; sl++) {
        uint4 t = p4[(size_t)sl * 65536 + i];
        unsigned uu[4] = {t.x, t.y, t.z, t.w};
#pragma unroll
        for (int j = 0; j < 4; j++) {
            s[2 * j]     += bf2f((unsigned short)(uu[j] & 0xffff));
            s[2 * j + 1] += bf2f((unsigned short)(uu[j] >> 16));
        }
    }
    float4* o4 = (float4*)out;
    o4[2 * i]     = make_float4(s[0], s[1], s[2], s[3]);
    o4[2 * i + 1] = make_float4(s[4], s[5], s[6], s[7]);
}

// ------- fused scoring + exact hierarchical rank-based top-k + softmax -------
__global__ __launch_bounds__(256) void score_topk(
    const float* __restrict__ qh, const float* __restrict__ bq,
    const float* __restrict__ keys, float* __restrict__ w) {
    int nt = blockIdx.x, h = blockIdx.y;
    int tid = threadIdx.x;
    int lane = tid & 63, wv = tid >> 6;

    __shared__ __align__(16) float q[128];
    __shared__ __align__(16) unsigned long long sk[2 * EXP];  // key1,key2 interleaved
    __shared__ float c1v[64], c2v[64];
    __shared__ unsigned long long c1k[64], c2k[64];
    __shared__ int c1e[64], c2e[64];
    __shared__ float t1v[16], t2v[16];
    __shared__ int   t1i[16], t2i[16];
    __shared__ __align__(16) unsigned long long ck[EXP];
    __shared__ float ccv[64];
    __shared__ unsigned long long cck[64];
    __shared__ int ccq[64];
    __shared__ float selv[16];
    __shared__ int   seli[16];

    if (tid < 128) q[tid] = qh[nt * HDK + h * DKH + tid] + bq[h * DKH + tid];
    __syncthreads();

    // s1[e], s2[e] fp32 dots over 64 -> sortable keys
    float v1, v2;
    {
        int e = tid;
        const float4* k1 = (const float4*)(keys + ((size_t)(h * 2 + 0) * EXP + e) * HALFD);
        const float4* k2 = (const float4*)(keys + ((size_t)(h * 2 + 1) * EXP + e) * HALFD);
        const float4* q1 = (const float4*)q;
        const float4* q2 = (const float4*)(q + 64);
        float a1 = 0.f, a2 = 0.f;
#pragma unroll
        for (int c = 0; c < 16; c++) {
            float4 ka = k1[c], qa = q1[c];
            a1 += ka.x * qa.x + ka.y * qa.y + ka.z * qa.z + ka.w * qa.w;
            float4 kb = k2[c], qb = q2[c];
            a2 += kb.x * qb.x + kb.y * qb.y + kb.z * qb.z + kb.w * qb.w;
        }
        v1 = a1; v2 = a2;
        sk[2 * e]     = mkkey(a1, e);
        sk[2 * e + 1] = mkkey(a2, e);
    }
    __syncthreads();

    // wave-local exact top-16 by rank within own 64-segment (keys distinct)
    {
        unsigned long long k1 = sk[2 * tid], k2 = sk[2 * tid + 1];
        int r1 = 0, r2 = 0, base = wv * 64;
#pragma unroll 4
        for (int j = 0; j < 64; j++) {
            ulonglong2 p = *(const ulonglong2*)&sk[2 * (base + j)];
            r1 += (p.x > k1);
            r2 += (p.y > k2);
        }
        if (r1 < 16) { c1k[wv * 16 + r1] = k1; c1v[wv * 16 + r1] = v1; c1e[wv * 16 + r1] = tid; }
        if (r2 < 16) { c2k[wv * 16 + r2] = k2; c2v[wv * 16 + r2] = v2; c2e[wv * 16 + r2] = tid; }
    }
    __syncthreads();

    // merge 64 candidates -> global top-16 (wave0: s1, wave1: s2)
    if (wv < 2) {
        const unsigned long long* ak = wv ? c2k : c1k;
        const float* av = wv ? c2v : c1v;
        const int*   ae = wv ? c2e : c1e;
        unsigned long long mk = ak[lane];
        int r = 0;
#pragma unroll 4
        for (int j = 0; j < 64; j++) r += (ak[j] > mk);
        if (r < 16) {
            if (wv == 0) { t1v[r] = av[lane]; t1i[r] = ae[lane]; }
            else         { t2v[r] = av[lane]; t2i[r] = ae[lane]; }
        }
    }
    __syncthreads();

    // 256 combo sums; exact top-16 again via local rank + merge
    float cval = t1v[tid >> 4] + t2v[tid & 15];
    ck[tid] = mkkey(cval, tid);
    __syncthreads();
    {
        unsigned long long k = ck[tid];
        int r = 0, base = wv * 64;
#pragma unroll 4
        for (int j = 0; j < 64; j += 2) {
            ulonglong2 p = *(const ulonglong2*)&ck[base + j];
            r += (p.x > k);
            r += (p.y > k);
        }
        if (r < 16) { cck[wv * 16 + r] = k; ccv[wv * 16 + r] = cval; ccq[wv * 16 + r] = tid; }
    }
    __syncthreads();
    if (wv == 0) {
        unsigned long long mk = cck[lane];
        int r = 0;
#pragma unroll 4
        for (int j = 0; j < 64; j++) r += (cck[j] > mk);
        if (r < 16) {
            int qq = ccq[lane];
            selv[r] = ccv[lane];
            seli[r] = t1i[qq >> 4] * EXP + t2i[qq & 15];
        }
    }
    __syncthreads();

    // softmax over the 16 selected, scatter into w
    if (tid < 16) {
        float val = selv[tid];
        float mx = selv[0];
#pragma unroll
        for (int j = 1; j < 16; j++) mx = fmaxf(mx, selv[j]);
        float sm = 0.f;
#pragma unroll
        for (int j = 0; j < 16; j++) sm += __expf(selv[j] - mx);
        atomicAdd(&w[seli[tid]], __expf(val - mx) / sm);
    }
}

// ---------------- launch ----------------
extern "C" void kernel_launch(void* const* d_in, const int* in_sizes, int n_in,
                              void* d_out, int out_size, void* d_ws, size_t ws_size,
                              hipStream_t stream) {
    const float* queries = (const float*)d_in[0];   // (2,512,512)
    const float* Wq      = (const float*)d_in[1];   // (1024,512)
    const float* bq      = (const float*)d_in[2];   // (1024)
    const float* keys    = (const float*)d_in[3];   // (8,2,256,64)
    const float* wd      = (const float*)d_in[4];   // (65536,512)
    const float* wu      = (const float*)d_in[5];   // (65536,512)
    float* out = (float*)d_out;                     // (2,512,512) fp32

    // workspace layout (196 MB)
    uint8_t* ws = (uint8_t*)d_ws;
    const size_t MB = 1048576;
    unsigned short* Qcat  = (unsigned short*)(ws);            // 0..3 MB (1024x1536)
    float*          w     = (float*)(ws + 3 * MB);            // 3..3.25 MB
    unsigned short* Wdh   = (unsigned short*)(ws + 4 * MB);   // 4..36 MB (32768x512)
    unsigned short* WuTh  = (unsigned short*)(ws + 36 * MB);  // 36..68 MB (512x32768)
    unsigned short* Cb    = (unsigned short*)(ws + 68 * MB);  // 68..132 MB (1024x32768)
    unsigned short* Ppart = (unsigned short*)(ws + 132 * MB); // 132..196 MB (64 slices bf16)
    // dead-after-score buffers alias the Ppart region (stream-ordered safe)
    unsigned short* Wqcat = (unsigned short*)(ws + 132 * MB); // 3 MB
    float*          qh    = (float*)(ws + 135 * MB);          // 4 MB

    hipMemsetAsync(w, 0, EE * sizeof(float), stream);

    cvt_pack<0><<<512, 256, 0, stream>>>(queries, Qcat);
    cvt_pack<1><<<512, 256, 0, stream>>>(Wq, Wqcat);

    // qh = Q @ Wq^T in ~fp32 via single K=1536 concat GEMM (bias in score_topk)
    gemm_bt<0><<<dim3(8, 8, 1), 256, 0, stream>>>(
        Qcat, 1536, Wqcat, 1536, 24, qh, nullptr, HDK, nullptr, 0);

    // scores, top-k, softmax -> w[e]
    score_topk<<<dim3(NTOK, NH), 256, 0, stream>>>(qh, bq, keys, w);

    // big GEMMs per e-half; converts reuse 32 MB buffers inside the loop
    for (int sp = 0; sp < 2; sp++) {
        cvt_bf16<<<8192, 256, 0, stream>>>(wd + (size_t)sp * 16777216, Wdh, 2097152);
        // C[t,e] = relu(Q . wd[e]) * w[e]   (M=1024, N=32768, K=512)
        gemm_bt<1><<<dim3(8, 256, 1), 256, 0, stream>>>(
            Qcat, 1536, Wdh, DIM, 8, nullptr, Cb, 32768, w + (size_t)sp * 32768, 0);
        transpose_wu<<<dim3(16, 1024), dim3(32, 8), 0, stream>>>(wu, WuTh, sp * 32768);
        // partial[z][t,d] = C[t,z-slice] . WuT[d,z-slice]  (split-K=32/half, bf16)
        gemm_bt<4><<<dim3(8, 4, 32), 256, 0, stream>>>(
            Cb, 32768, WuTh, 32768, 16, nullptr,
            Ppart + (size_t)sp * 32 * 524288, DIM, nullptr, 524288);
    }
    // out = sum of 64 bf16 partial slices
    reduce_part<<<256, 256, 0, stream>>>(Ppart, out);
}